// Round 6
// baseline (723.937 us; speedup 1.0000x reference)
//
#include <hip/hip_runtime.h>

// f32 I/O. K=8 expert AEs, B=8192, D=1024, H=256.
//   h = relu(x @ W1[k] + b1[k]); recon = h @ W2[k] + b2[k]
//   err[k,b] = mean((recon-x)^2); out[b] = recon[argmin_k err, b]
// Precision (validated R2): pass1 err via split-bf16 hi/lo 3-product GEMMs;
// pass2 winner recon plain bf16-hi.
// R6 (verified 428us, pass1 230us): 2-stage reg dbuf phase A; phase B
// h-in-regs per mc-pass, W2 x2. R7/R8/R9 restructures regressed.
// R10 (swizzle): FETCH -20% but time FLAT -> latency-bound, not BW-bound.
// Occupancy pinned at 2 waves/SIMD by BOTH 192 unified regs (128V+64A) AND
// 64KB LDS. R11 (this rev) unpins both -> 3 waves/SIMD (12/CU, +50% TLP):
//  - LDS 64->32KB: two-pass h-exchange by row-halves (rows 0-31, then 32-63
//    overwrite the same 32KB; dt-loops stay barrier-free; +2 barriers).
//  - regs ->~170: x stream stays 2-stage (LLC-latency, needs deep cover);
//    W1 thinned to nt-pair chunks w/ 1-chunk lookahead (L2-resident, 3 waves
//    cover residual). __launch_bounds__(256,3).
//  - decode reverted to R6 (k=bx&7: XCD=expert, W resident, x dedup'd).
// Tripwires: WRITE_SIZE >1MB = spill; Occupancy ~23% = alloc failed the cap.

#define KE 8
#define NB 8192
#define ND 1024
#define NH 256

typedef float f32x4 __attribute__((ext_vector_type(4)));
typedef short s16x8 __attribute__((ext_vector_type(8)));
typedef unsigned short u16x8 __attribute__((ext_vector_type(8)));

__device__ __forceinline__ float bf2f(unsigned short h) {
  union { unsigned int u; float f; } v; v.u = ((unsigned int)h) << 16; return v.f;
}
__device__ __forceinline__ unsigned short f2bf(float f) {
  union { unsigned int u; float f; } v; v.f = f;
  unsigned int u = v.u;
  u += 0x7fffu + ((u >> 16) & 1u);   // RTNE
  return (unsigned short)(u >> 16);
}
__device__ __forceinline__ void split2(float x, unsigned short& hi, unsigned short& lo) {
  hi = f2bf(x);
  lo = f2bf(x - bf2f(hi));
}

// ---- fused pack: W1, W2, x -> frag-ordered hi/lo arrays; also zeroes cnt.
__global__ __launch_bounds__(256) void pack_all(
    const float* __restrict__ W1, unsigned short* __restrict__ w1oh, unsigned short* __restrict__ w1ol,
    const float* __restrict__ W2, unsigned short* __restrict__ w2oh, unsigned short* __restrict__ w2ol,
    const float* __restrict__ xin, unsigned short* __restrict__ xoh, unsigned short* __restrict__ xol,
    unsigned int* __restrict__ cnt) {
  const int bx = blockIdx.x;
  const int tid = threadIdx.x;
  if (bx == 0 && tid < KE) cnt[tid] = 0;

  if (bx < 1024) {                           // ---- pack W1
    int gid = bx * 256 + tid;
    int L = gid & 63;
    int g = gid >> 6;
    int ks = g & 31;
    int ct = (g >> 5) & 15;
    int k = g >> 9;
    int col = ct * 16 + (L & 15);
    int kd0 = ks * 32 + (L >> 4) * 8;
    unsigned short th[8], tl[8];
#pragma unroll
    for (int j = 0; j < 8; ++j) {
      float v = W1[((size_t)k * ND + kd0 + j) * NH + col];
      split2(v, th[j], tl[j]);
    }
    size_t o = ((size_t)g * 64 + L) * 8;
    *(u16x8*)&w1oh[o] = *(u16x8*)th;
    *(u16x8*)&w1ol[o] = *(u16x8*)tl;
  } else if (bx < 2048) {                    // ---- pack W2
    int gid = (bx - 1024) * 256 + tid;
    int L = gid & 63;
    int g = gid >> 6;
    int ks = g & 7;
    int dt = (g >> 3) & 63;
    int k = g >> 9;
    int d2 = dt * 16 + (L & 15);
    int h0 = ks * 32 + (L >> 4) * 8;
    unsigned short th[8], tl[8];
#pragma unroll
    for (int j = 0; j < 8; ++j) {
      float v = W2[((size_t)k * NH + h0 + j) * ND + d2];
      split2(v, th[j], tl[j]);
    }
    size_t o = ((size_t)g * 64 + L) * 8;
    *(u16x8*)&w2oh[o] = *(u16x8*)th;
    *(u16x8*)&w2ol[o] = *(u16x8*)tl;
  } else {                                   // ---- pack x
    int gid = (bx - 2048) * 256 + tid;
    int L = gid & 63;
    int g = gid >> 6;
    int ks = g & 31;
    int rt = g >> 5;
    int row = rt * 16 + (L & 15);
    int kd0 = ks * 32 + (L >> 4) * 8;
    float4 a = *(const float4*)&xin[(size_t)row * ND + kd0];
    float4 b = *(const float4*)&xin[(size_t)row * ND + kd0 + 4];
    unsigned short th[8], tl[8];
    split2(a.x, th[0], tl[0]); split2(a.y, th[1], tl[1]);
    split2(a.z, th[2], tl[2]); split2(a.w, th[3], tl[3]);
    split2(b.x, th[4], tl[4]); split2(b.y, th[5], tl[5]);
    split2(b.z, th[6], tl[6]); split2(b.w, th[7], tl[7]);
    size_t o = ((size_t)g * 64 + L) * 8;
    *(u16x8*)&xoh[o] = *(u16x8*)th;
    *(u16x8*)&xol[o] = *(u16x8*)tl;
  }
}

// x frags for one it: 4 mt x hi/lo (8 frags, 32 VGPR)
#define XLOAD(xh_, xl_, it)                         \
  do {                                              \
    _Pragma("unroll")                               \
    for (int m_ = 0; m_ < 4; ++m_) {                \
      int o_ = xo[m_] + (it) * 512;                 \
      xh_[m_] = *(const s16x8*)&xph[o_];            \
      xl_[m_] = *(const s16x8*)&xpl[o_];            \
    }                                               \
  } while (0)

// W1 frags for one nt-pair chunk: 2 nt x hi/lo (4 frags, 16 VGPR)
#define WLOAD(wh_, wl_, it, c)                      \
  do {                                              \
    _Pragma("unroll")                               \
    for (int j_ = 0; j_ < 2; ++j_) {                \
      int o_ = wo1[(c)*2 + j_] + (it) * 512;        \
      wh_[j_] = *(const s16x8*)&w1ph[o_];           \
      wl_[j_] = *(const s16x8*)&w1pl[o_];           \
    }                                               \
  } while (0)

// 24 MFMAs (3-product split) on one nt-pair chunk
#define MFMA24(xh_, xl_, wh_, wl_, c)                                                                      \
  do {                                                                                                     \
    _Pragma("unroll")                                                                                      \
    for (int j_ = 0; j_ < 2; ++j_)                                                                         \
      _Pragma("unroll")                                                                                    \
      for (int m_ = 0; m_ < 4; ++m_) {                                                                     \
        acc1[m_][(c)*2+j_] = __builtin_amdgcn_mfma_f32_16x16x32_bf16(xh_[m_], wh_[j_], acc1[m_][(c)*2+j_], 0, 0, 0); \
        acc1[m_][(c)*2+j_] = __builtin_amdgcn_mfma_f32_16x16x32_bf16(xh_[m_], wl_[j_], acc1[m_][(c)*2+j_], 0, 0, 0); \
        acc1[m_][(c)*2+j_] = __builtin_amdgcn_mfma_f32_16x16x32_bf16(xl_[m_], wh_[j_], acc1[m_][(c)*2+j_], 0, 0, 0); \
      }                                                                                                    \
  } while (0)

// epilogue half: +b1, relu, split, write 2 row-tiles (mt0, mt0+1) into hx
#define EPIPART(mt0)                                                        \
  do {                                                                      \
    _Pragma("unroll")                                                       \
    for (int nt_ = 0; nt_ < 4; ++nt_) {                                     \
      float b1v_ = b1[(size_t)k * NH + wv * 64 + nt_ * 16 + lo];            \
      _Pragma("unroll")                                                     \
      for (int mm_ = 0; mm_ < 2; ++mm_)                                     \
        _Pragma("unroll")                                                   \
        for (int i_ = 0; i_ < 4; ++i_) {                                    \
          float v_ = acc1[(mt0) + mm_][nt_][i_] + b1v_;                     \
          v_ = v_ > 0.f ? v_ : 0.f;                                         \
          unsigned short vh_, vl_;                                          \
          split2(v_, vh_, vl_);                                             \
          int rl_ = mm_ * 16 + quad * 4 + i_;                               \
          int col_ = wv * 64 + nt_ * 16 + lo;                               \
          int sc_ = col_ ^ ((rl_ & 7) << 3);                                \
          s.hx.h[rl_][sc_] = vh_;                                           \
          s.hx.l[rl_][sc_] = vl_;                                           \
        }                                                                   \
    }                                                                       \
  } while (0)

// ---- pass 1: split-precision err[K][B]. BM=64, grid 1024, expert = bx & 7.
__global__ __launch_bounds__(256, 3) void ae_pass1(
    const unsigned short* __restrict__ xph, const unsigned short* __restrict__ xpl,
    const float* __restrict__ x,
    const unsigned short* __restrict__ w1ph, const unsigned short* __restrict__ w1pl,
    const float* __restrict__ b1,
    const unsigned short* __restrict__ w2ph, const unsigned short* __restrict__ w2pl,
    const float* __restrict__ b2, float* __restrict__ err) {
  __shared__ union {
    struct { unsigned short h[32][256]; unsigned short l[32][256]; } hx;  // 32768 B
    float errp[4][64];
  } s;

  const int tid = threadIdx.x;
  const int wv = tid >> 6;
  const int lane = tid & 63;
  const int lo = lane & 15;
  const int quad = lane >> 4;
  const int k = blockIdx.x & 7;          // XCD = expert: W1/W2[k] L2-resident
  const int rtile = blockIdx.x >> 3;
  const int r0 = rtile * 64;

  // ---------- phase A: h = relu(x@W1+b1). Barrier-free.
  // x 2-stage double-buffer (deep cover for LLC-latency stream);
  // W1 nt-pair chunks with 1-chunk lookahead (L2-resident stream).
  int xo[4], wo1[4];
#pragma unroll
  for (int mt = 0; mt < 4; ++mt) xo[mt] = ((rtile * 4 + mt) * 32) * 512 + lane * 8;
#pragma unroll
  for (int nt = 0; nt < 4; ++nt) wo1[nt] = ((k * 16 + wv * 4 + nt) * 32) * 512 + lane * 8;

  f32x4 acc1[4][4];
#pragma unroll
  for (int mt = 0; mt < 4; ++mt)
#pragma unroll
    for (int nt = 0; nt < 4; ++nt) acc1[mt][nt] = (f32x4){0.f, 0.f, 0.f, 0.f};

  s16x8 XAh[4], XAl[4], XBh[4], XBl[4];     // 64 VGPR
  s16x8 W0h[2], W0l[2], W1h_[2], W1l_[2];   // 32 VGPR
  XLOAD(XAh, XAl, 0);
  WLOAD(W0h, W0l, 0, 0);
  for (int it = 0; it < 32; it += 2) {
    // sub-it A (even it): consume XA; prefetch XB + next W chunks
    XLOAD(XBh, XBl, it + 1);
    WLOAD(W1h_, W1l_, it, 1);
    MFMA24(XAh, XAl, W0h, W0l, 0);
    WLOAD(W0h, W0l, it + 1, 0);
    MFMA24(XAh, XAl, W1h_, W1l_, 1);
    // sub-it B (odd it): consume XB; prefetch XA for it+2
    if (it + 2 < 32) XLOAD(XAh, XAl, it + 2);
    WLOAD(W1h_, W1l_, it + 1, 1);
    MFMA24(XBh, XBl, W0h, W0l, 0);
    if (it + 2 < 32) WLOAD(W0h, W0l, it + 2, 0);
    MFMA24(XBh, XBl, W1h_, W1l_, 1);
  }

  // ---------- two-pass h exchange + phase B (W2 streamed per mc pass)
  float eacc[4][4];
#pragma unroll
  for (int mt = 0; mt < 4; ++mt)
#pragma unroll
    for (int i = 0; i < 4; ++i) eacc[mt][i] = 0.f;

  const int w2base = ((k * 64 + wv * 16) * 8) * 512 + lane * 8;

  EPIPART(0);              // write h rows 0-31 (hi+lo) into hx
  __syncthreads();         // (1) rows 0-31 visible

  s16x8 hh[2][8], hl[2][8];
#pragma unroll
  for (int m2 = 0; m2 < 2; ++m2) {         // preload mc=0 frags
    int row = m2 * 16 + lo;
    int rbase = row * 256;
    int sw = (row & 7) << 3;
#pragma unroll
    for (int ks = 0; ks < 8; ++ks) {
      int off = rbase + ((ks * 32 + quad * 8) ^ sw);
      hh[m2][ks] = *(const s16x8*)(&s.hx.h[0][0] + off);
      hl[m2][ks] = *(const s16x8*)(&s.hx.l[0][0] + off);
    }
  }
  __syncthreads();         // (2) all mc=0 preloads done
  EPIPART(2);              // overwrite hx with h rows 32-63
  __syncthreads();         // (3) rows 32-63 visible

  // mc=0 dt-loop (barrier-free)
  for (int dt = 0; dt < 16; ++dt) {
    f32x4 acc2[2];
    acc2[0] = (f32x4){0.f, 0.f, 0.f, 0.f};
    acc2[1] = (f32x4){0.f, 0.f, 0.f, 0.f};
#pragma unroll
    for (int ks = 0; ks < 8; ++ks) {
      int wo = w2base + dt * 4096 + ks * 512;
      s16x8 bh = *(const s16x8*)&w2ph[wo];
      s16x8 bl = *(const s16x8*)&w2pl[wo];
#pragma unroll
      for (int m2 = 0; m2 < 2; ++m2) {
        acc2[m2] = __builtin_amdgcn_mfma_f32_16x16x32_bf16(hh[m2][ks], bh, acc2[m2], 0, 0, 0);
        acc2[m2] = __builtin_amdgcn_mfma_f32_16x16x32_bf16(hh[m2][ks], bl, acc2[m2], 0, 0, 0);
        acc2[m2] = __builtin_amdgcn_mfma_f32_16x16x32_bf16(hl[m2][ks], bh, acc2[m2], 0, 0, 0);
      }
    }
    const int d2 = wv * 256 + dt * 16 + lo;
    float b2v = b2[(size_t)k * ND + d2];
#pragma unroll
    for (int m2 = 0; m2 < 2; ++m2)
#pragma unroll
      for (int i = 0; i < 4; ++i) {
        int row = m2 * 16 + quad * 4 + i;
        float rec = acc2[m2][i] + b2v;
        float xv = x[(size_t)(r0 + row) * ND + d2];
        float dd = rec - xv;
        eacc[m2][i] += dd * dd;
      }
  }

  // preload mc=1 frags (hx stable since barrier 3)
#pragma unroll
  for (int m2 = 0; m2 < 2; ++m2) {
    int row = m2 * 16 + lo;
    int rbase = row * 256;
    int sw = (row & 7) << 3;
#pragma unroll
    for (int ks = 0; ks < 8; ++ks) {
      int off = rbase + ((ks * 32 + quad * 8) ^ sw);
      hh[m2][ks] = *(const s16x8*)(&s.hx.h[0][0] + off);
      hl[m2][ks] = *(const s16x8*)(&s.hx.l[0][0] + off);
    }
  }

  // mc=1 dt-loop (rows 32-63)
  for (int dt = 0; dt < 16; ++dt) {
    f32x4 acc2[2];
    acc2[0] = (f32x4){0.f, 0.f, 0.f, 0.f};
    acc2[1] = (f32x4){0.f, 0.f, 0.f, 0.f};
#pragma unroll
    for (int ks = 0; ks < 8; ++ks) {
      int wo = w2base + dt * 4096 + ks * 512;
      s16x8 bh = *(const s16x8*)&w2ph[wo];
      s16x8 bl = *(const s16x8*)&w2pl[wo];
#pragma unroll
      for (int m2 = 0; m2 < 2; ++m2) {
        acc2[m2] = __builtin_amdgcn_mfma_f32_16x16x32_bf16(hh[m2][ks], bh, acc2[m2], 0, 0, 0);
        acc2[m2] = __builtin_amdgcn_mfma_f32_16x16x32_bf16(hh[m2][ks], bl, acc2[m2], 0, 0, 0);
        acc2[m2] = __builtin_amdgcn_mfma_f32_16x16x32_bf16(hl[m2][ks], bh, acc2[m2], 0, 0, 0);
      }
    }
    const int d2 = wv * 256 + dt * 16 + lo;
    float b2v = b2[(size_t)k * ND + d2];
#pragma unroll
    for (int m2 = 0; m2 < 2; ++m2)
#pragma unroll
      for (int i = 0; i < 4; ++i) {
        int row = 32 + m2 * 16 + quad * 4 + i;
        float rec = acc2[m2][i] + b2v;
        float xv = x[(size_t)(r0 + row) * ND + d2];
        float dd = rec - xv;
        eacc[2 + m2][i] += dd * dd;
      }
  }

  __syncthreads();   // (4) all hx reads done before errp aliases the union
#pragma unroll
  for (int mt = 0; mt < 4; ++mt)
#pragma unroll
    for (int i = 0; i < 4; ++i) {
      float v = eacc[mt][i];
      v += __shfl_xor(v, 1, 16);
      v += __shfl_xor(v, 2, 16);
      v += __shfl_xor(v, 4, 16);
      v += __shfl_xor(v, 8, 16);
      if (lo == 0) s.errp[wv][mt * 16 + quad * 4 + i] = v;
    }
  __syncthreads();   // (5)
  if (tid < 64)
    err[(size_t)k * NB + r0 + tid] =
        (s.errp[0][tid] + s.errp[1][tid] + s.errp[2][tid] + s.errp[3][tid]) * (1.0f / (float)ND);
}

// ---- argmin + bucket rows per expert
__global__ __launch_bounds__(256) void ae_argmin(const float* __restrict__ err,
                                                 unsigned int* __restrict__ cnt,
                                                 int* __restrict__ bucket) {
  __shared__ unsigned int lc[KE];
  __shared__ unsigned int base[KE];
  int tid = threadIdx.x;
  if (tid < KE) lc[tid] = 0;
  __syncthreads();
  int b = blockIdx.x * 256 + tid;
  float best = err[b];
  int kmin = 0;
#pragma unroll
  for (int j = 1; j < KE; ++j) {
    float e = err[(size_t)j * NB + b];
    if (e < best) { best = e; kmin = j; }   // strict < == first-min (jnp.argmin)
  }
  unsigned int lpos = atomicAdd(&lc[kmin], 1u);
  __syncthreads();
  if (tid < KE) base[tid] = atomicAdd(&cnt[tid], lc[tid]);
  __syncthreads();
  bucket[(size_t)kmin * NB + (int)(base[kmin] + lpos)] = b;
}

// ---- pass 2: recompute winner rows (bf16-hi, packed W frags), write f32 out
__global__ __launch_bounds__(256) void ae_pass2(
    const float* __restrict__ x,
    const unsigned short* __restrict__ w1ph, const float* __restrict__ b1,
    const unsigned short* __restrict__ w2ph, const float* __restrict__ b2,
    const unsigned int* __restrict__ cnt, const int* __restrict__ bucket,
    float* __restrict__ out) {
  __shared__ unsigned short hs[64][NH + 8];   // 33792 B
  __shared__ unsigned short xs[64][40];       // 5120 B
  __shared__ int rid[64];

  const int k = blockIdx.x & 7;
  const int cv = (int)cnt[k];
  const int t0 = (blockIdx.x >> 3) * 64;
  if (t0 >= cv) return;                     // uniform exit before any barrier
  const int nrows = min(64, cv - t0);

  const int tid = threadIdx.x;
  const int wv = tid >> 6;
  const int lane = tid & 63;
  const int lo = lane & 15;
  const int quad = lane >> 4;
  const int srow = tid >> 2, scol = (tid & 3) * 8;

  if (tid < 64) {
    int idx = t0 + tid;
    rid[tid] = bucket[(size_t)k * NB + (idx < cv ? idx : t0)];
  }
  __syncthreads();
  const int grow = rid[srow];

  f32x4 acc1[4][4];
#pragma unroll
  for (int mt = 0; mt < 4; ++mt)
#pragma unroll
    for (int nt = 0; nt < 4; ++nt) acc1[mt][nt] = (f32x4){0.f, 0.f, 0.f, 0.f};

  for (int it = 0; it < 32; ++it) {
    float4 xa = *(const float4*)&x[(size_t)grow * ND + it * 32 + scol];
    float4 xb = *(const float4*)&x[(size_t)grow * ND + it * 32 + scol + 4];
    s16x8 bfr[4];
#pragma unroll
    for (int nt = 0; nt < 4; ++nt)
      bfr[nt] = *(const s16x8*)&w1ph[(((size_t)(k * 16 + wv * 4 + nt) * 32) + it) * 512 + lane * 8];
    __syncthreads();   // prev frag reads done
    unsigned short t[8];
    t[0] = f2bf(xa.x); t[1] = f2bf(xa.y); t[2] = f2bf(xa.z); t[3] = f2bf(xa.w);
    t[4] = f2bf(xb.x); t[5] = f2bf(xb.y); t[6] = f2bf(xb.z); t[7] = f2bf(xb.w);
    *(u16x8*)&xs[srow][scol] = *(u16x8*)t;
    __syncthreads();
    s16x8 af[4];
#pragma unroll
    for (int mt = 0; mt < 4; ++mt) af[mt] = *(const s16x8*)&xs[mt * 16 + lo][quad * 8];
#pragma unroll
    for (int mt = 0; mt < 4; ++mt)
#pragma unroll
      for (int nt = 0; nt < 4; ++nt)
        acc1[mt][nt] = __builtin_amdgcn_mfma_f32_16x16x32_bf16(af[mt], bfr[nt], acc1[mt][nt], 0, 0, 0);
  }
  __syncthreads();

#pragma unroll
  for (int nt = 0; nt < 4; ++nt) {
    float b1v = b1[(size_t)k * NH + wv * 64 + nt * 16 + lo];
#pragma unroll
    for (int mt = 0; mt < 4; ++mt)
#pragma unroll
      for (int i = 0; i < 4; ++i) {
        float v = acc1[mt][nt][i] + b1v;
        v = v > 0.f ? v : 0.f;
        hs[mt * 16 + quad * 4 + i][wv * 64 + nt * 16 + lo] = f2bf(v);
      }
  }
  __syncthreads();

  // phase B: wave wv owns rows [wv*16, +16); d2 chunks of 32; no barriers.
  for (int c = 0; c < 32; ++c) {
    f32x4 acc2[2];
    acc2[0] = (f32x4){0.f, 0.f, 0.f, 0.f};
    acc2[1] = (f32x4){0.f, 0.f, 0.f, 0.f};
#pragma unroll
    for (int ks = 0; ks < 8; ++ks) {
      s16x8 af = *(const s16x8*)&hs[wv * 16 + lo][ks * 32 + quad * 8];
#pragma unroll
      for (int nt = 0; nt < 2; ++nt) {
        s16x8 bfr = *(const s16x8*)&w2ph[(((size_t)(k * 64 + c * 2 + nt) * 8) + ks) * 512 + lane * 8];
        acc2[nt] = __builtin_amdgcn_mfma_f32_16x16x32_bf16(af, bfr, acc2[nt], 0, 0, 0);
      }
    }
#pragma unroll
    for (int nt = 0; nt < 2; ++nt) {
      float b2v = b2[(size_t)k * ND + c * 32 + nt * 16 + lo];
#pragma unroll
      for (int i = 0; i < 4; ++i) {
        int row = wv * 16 + quad * 4 + i;
        if (row < nrows)
          out[(size_t)rid[row] * ND + c * 32 + nt * 16 + lo] = acc2[nt][i] + b2v;
      }
    }
  }
}

extern "C" void kernel_launch(void* const* d_in, const int* in_sizes, int n_in,
                              void* d_out, int out_size, void* d_ws, size_t ws_size,
                              hipStream_t stream) {
  (void)in_sizes; (void)n_in; (void)out_size; (void)ws_size;
  const float* x  = (const float*)d_in[0];
  const float* W1 = (const float*)d_in[1];
  const float* b1 = (const float*)d_in[2];
  const float* W2 = (const float*)d_in[3];
  const float* b2 = (const float*)d_in[4];
  float* out = (float*)d_out;

  char* ws = (char*)d_ws;
  const size_t szW = (size_t)KE * ND * NH * sizeof(unsigned short);  // 4 MB
  const size_t szX = (size_t)NB * ND * sizeof(unsigned short);       // 16.78 MB
  unsigned short* w1ph = (unsigned short*)(ws);
  unsigned short* w1pl = (unsigned short*)(ws + szW);
  unsigned short* w2ph = (unsigned short*)(ws + 2 * szW);
  unsigned short* w2pl = (unsigned short*)(ws + 3 * szW);
  unsigned short* xph  = (unsigned short*)(ws + 4 * szW);
  unsigned short* xpl  = (unsigned short*)(ws + 4 * szW + szX);
  char* tail           = ws + 4 * szW + 2 * szX;
  float* err           = (float*)tail;
  int* bucket          = (int*)(tail + (size_t)KE * NB * sizeof(float));
  unsigned int* cnt    = (unsigned int*)(tail + (size_t)KE * NB * sizeof(float)
                                         + (size_t)KE * NB * sizeof(int));
  // ws use ~50 MB

  pack_all<<<6144, 256, 0, stream>>>(W1, w1ph, w1pl, W2, w2ph, w2pl, x, xph, xpl, cnt);
  ae_pass1<<<1024, 256, 0, stream>>>(xph, xpl, x, w1ph, w1pl, b1, w2ph, w2pl, b2, err);
  ae_argmin<<<NB / 256, 256, 0, stream>>>(err, cnt, bucket);
  ae_pass2<<<1024, 256, 0, stream>>>(x, w1ph, b1, w2ph, b2, cnt, bucket, out);
}

// Round 7
// 449.858 us; speedup vs baseline: 1.6093x; 1.6093x over previous
//
#include <hip/hip_runtime.h>

// f32 I/O. K=8 expert AEs, B=8192, D=1024, H=256.
//   h = relu(x @ W1[k] + b1[k]); recon = h @ W2[k] + b2[k]
//   err[k,b] = mean((recon-x)^2); out[b] = recon[argmin_k err, b]
// Precision (validated R2): pass1 err via split-bf16 hi/lo 3-product GEMMs;
// pass2 winner recon plain bf16-hi.
// R6 (verified 428us, pass1 230us, MfmaUtil 40%): 2-stage reg dbuf phase A;
// phase B h-in-regs per mc-pass, W2 streamed twice. R7/R8/R9 restructures
// regressed; R10 swizzle: traffic -20% but time flat (latency-bound);
// R11 (256,3)-cap: allocator spilled (VGPR 84, WRITE 152MB), occupancy flat.
// => 2 waves/SIMD is the operating point; the lever is PIPELINE DEPTH within
// the 256-reg/wave budget (R6 used only ~210).
// R12 (this rev) = exact R6 + deeper phase-A pipeline, depth matched to
// per-stream latency:
//  - x (LLC/HBM-latency stream, shared across XCDs): 3-stage rotating reg
//    buffer, loaded 3 its ahead (~600cy/wave cover, ~1200 w/ co-wave).
//  - W1 (L2-resident under k=bx&7 decode): nt-pair chunks, 1-chunk lookahead.
//  - hot loop = 9 groups x 3 its, branch-free; its 27-31 peeled.
// Tripwire: WRITE_SIZE >1MB = spill -> revert, attack phase B instead.

#define KE 8
#define NB 8192
#define ND 1024
#define NH 256

typedef float f32x4 __attribute__((ext_vector_type(4)));
typedef short s16x8 __attribute__((ext_vector_type(8)));
typedef unsigned short u16x8 __attribute__((ext_vector_type(8)));

__device__ __forceinline__ float bf2f(unsigned short h) {
  union { unsigned int u; float f; } v; v.u = ((unsigned int)h) << 16; return v.f;
}
__device__ __forceinline__ unsigned short f2bf(float f) {
  union { unsigned int u; float f; } v; v.f = f;
  unsigned int u = v.u;
  u += 0x7fffu + ((u >> 16) & 1u);   // RTNE
  return (unsigned short)(u >> 16);
}
__device__ __forceinline__ void split2(float x, unsigned short& hi, unsigned short& lo) {
  hi = f2bf(x);
  lo = f2bf(x - bf2f(hi));
}

// ---- fused pack: W1, W2, x -> frag-ordered hi/lo arrays; also zeroes cnt.
__global__ __launch_bounds__(256) void pack_all(
    const float* __restrict__ W1, unsigned short* __restrict__ w1oh, unsigned short* __restrict__ w1ol,
    const float* __restrict__ W2, unsigned short* __restrict__ w2oh, unsigned short* __restrict__ w2ol,
    const float* __restrict__ xin, unsigned short* __restrict__ xoh, unsigned short* __restrict__ xol,
    unsigned int* __restrict__ cnt) {
  const int bx = blockIdx.x;
  const int tid = threadIdx.x;
  if (bx == 0 && tid < KE) cnt[tid] = 0;

  if (bx < 1024) {                           // ---- pack W1
    int gid = bx * 256 + tid;
    int L = gid & 63;
    int g = gid >> 6;
    int ks = g & 31;
    int ct = (g >> 5) & 15;
    int k = g >> 9;
    int col = ct * 16 + (L & 15);
    int kd0 = ks * 32 + (L >> 4) * 8;
    unsigned short th[8], tl[8];
#pragma unroll
    for (int j = 0; j < 8; ++j) {
      float v = W1[((size_t)k * ND + kd0 + j) * NH + col];
      split2(v, th[j], tl[j]);
    }
    size_t o = ((size_t)g * 64 + L) * 8;
    *(u16x8*)&w1oh[o] = *(u16x8*)th;
    *(u16x8*)&w1ol[o] = *(u16x8*)tl;
  } else if (bx < 2048) {                    // ---- pack W2
    int gid = (bx - 1024) * 256 + tid;
    int L = gid & 63;
    int g = gid >> 6;
    int ks = g & 7;
    int dt = (g >> 3) & 63;
    int k = g >> 9;
    int d2 = dt * 16 + (L & 15);
    int h0 = ks * 32 + (L >> 4) * 8;
    unsigned short th[8], tl[8];
#pragma unroll
    for (int j = 0; j < 8; ++j) {
      float v = W2[((size_t)k * NH + h0 + j) * ND + d2];
      split2(v, th[j], tl[j]);
    }
    size_t o = ((size_t)g * 64 + L) * 8;
    *(u16x8*)&w2oh[o] = *(u16x8*)th;
    *(u16x8*)&w2ol[o] = *(u16x8*)tl;
  } else {                                   // ---- pack x
    int gid = (bx - 2048) * 256 + tid;
    int L = gid & 63;
    int g = gid >> 6;
    int ks = g & 31;
    int rt = g >> 5;
    int row = rt * 16 + (L & 15);
    int kd0 = ks * 32 + (L >> 4) * 8;
    float4 a = *(const float4*)&xin[(size_t)row * ND + kd0];
    float4 b = *(const float4*)&xin[(size_t)row * ND + kd0 + 4];
    unsigned short th[8], tl[8];
    split2(a.x, th[0], tl[0]); split2(a.y, th[1], tl[1]);
    split2(a.z, th[2], tl[2]); split2(a.w, th[3], tl[3]);
    split2(b.x, th[4], tl[4]); split2(b.y, th[5], tl[5]);
    split2(b.z, th[6], tl[6]); split2(b.w, th[7], tl[7]);
    size_t o = ((size_t)g * 64 + L) * 8;
    *(u16x8*)&xoh[o] = *(u16x8*)th;
    *(u16x8*)&xol[o] = *(u16x8*)tl;
  }
}

// x frags for one it: 4 mt x hi/lo (8 frags, 32 VGPR)
#define XLOAD(xh_, xl_, it)                         \
  do {                                              \
    _Pragma("unroll")                               \
    for (int m_ = 0; m_ < 4; ++m_) {                \
      int o_ = xo[m_] + (it) * 512;                 \
      xh_[m_] = *(const s16x8*)&xph[o_];            \
      xl_[m_] = *(const s16x8*)&xpl[o_];            \
    }                                               \
  } while (0)

// W1 frags for one nt-pair chunk: 2 nt x hi/lo (4 frags, 16 VGPR)
#define WLOAD(wh_, wl_, it, c)                      \
  do {                                              \
    _Pragma("unroll")                               \
    for (int j_ = 0; j_ < 2; ++j_) {                \
      int o_ = wo1[(c)*2 + j_] + (it) * 512;        \
      wh_[j_] = *(const s16x8*)&w1ph[o_];           \
      wl_[j_] = *(const s16x8*)&w1pl[o_];           \
    }                                               \
  } while (0)

// 24 MFMAs (3-product split) on one nt-pair chunk
#define MFMA24(xh_, xl_, wh_, wl_, c)                                                                      \
  do {                                                                                                     \
    _Pragma("unroll")                                                                                      \
    for (int j_ = 0; j_ < 2; ++j_)                                                                         \
      _Pragma("unroll")                                                                                    \
      for (int m_ = 0; m_ < 4; ++m_) {                                                                     \
        acc1[m_][(c)*2+j_] = __builtin_amdgcn_mfma_f32_16x16x32_bf16(xh_[m_], wh_[j_], acc1[m_][(c)*2+j_], 0, 0, 0); \
        acc1[m_][(c)*2+j_] = __builtin_amdgcn_mfma_f32_16x16x32_bf16(xh_[m_], wl_[j_], acc1[m_][(c)*2+j_], 0, 0, 0); \
        acc1[m_][(c)*2+j_] = __builtin_amdgcn_mfma_f32_16x16x32_bf16(xl_[m_], wh_[j_], acc1[m_][(c)*2+j_], 0, 0, 0); \
      }                                                                                                    \
  } while (0)

// one it: consume X buf (it), W chunks via Wa/Wb rotation; prefetch X <- it+3.
// PF_W: load Wa <- (it+1, chunk0); PF_X: load X <- it+3.
#define IT_BODY(Xh_, Xl_, it, PF_W, PF_X)           \
  do {                                              \
    WLOAD(Wbh, Wbl, (it), 1);                       \
    MFMA24(Xh_, Xl_, Wah, Wal, 0);                  \
    if (PF_W) WLOAD(Wah, Wal, (it) + 1, 0);         \
    MFMA24(Xh_, Xl_, Wbh, Wbl, 1);                  \
    if (PF_X) XLOAD(Xh_, Xl_, (it) + 3);            \
  } while (0)

// ---- pass 1: split-precision err[K][B]. BM=64, grid 1024, expert = bx & 7.
__global__ __launch_bounds__(256, 2) void ae_pass1(
    const unsigned short* __restrict__ xph, const unsigned short* __restrict__ xpl,
    const float* __restrict__ x,
    const unsigned short* __restrict__ w1ph, const unsigned short* __restrict__ w1pl,
    const float* __restrict__ b1,
    const unsigned short* __restrict__ w2ph, const unsigned short* __restrict__ w2pl,
    const float* __restrict__ b2, float* __restrict__ err) {
  __shared__ union {
    struct { unsigned short h[64][256]; unsigned short l[64][256]; } hs;  // 65536 B
    float errp[4][64];
  } s;

  const int tid = threadIdx.x;
  const int wv = tid >> 6;
  const int lane = tid & 63;
  const int lo = lane & 15;
  const int quad = lane >> 4;
  const int k = blockIdx.x & 7;          // XCD = expert: W1/W2[k] L2-resident
  const int rtile = blockIdx.x >> 3;
  const int r0 = rtile * 64;

  // ---------- phase A: h = relu(x@W1+b1). Barrier-free, 3-stage x pipeline.
  int xo[4], wo1[4];
#pragma unroll
  for (int mt = 0; mt < 4; ++mt) xo[mt] = ((rtile * 4 + mt) * 32) * 512 + lane * 8;
#pragma unroll
  for (int nt = 0; nt < 4; ++nt) wo1[nt] = ((k * 16 + wv * 4 + nt) * 32) * 512 + lane * 8;

  f32x4 acc1[4][4];
#pragma unroll
  for (int mt = 0; mt < 4; ++mt)
#pragma unroll
    for (int nt = 0; nt < 4; ++nt) acc1[mt][nt] = (f32x4){0.f, 0.f, 0.f, 0.f};

  s16x8 X0h[4], X0l[4], X1h[4], X1l[4], X2h[4], X2l[4];   // 96 VGPR
  s16x8 Wah[2], Wal[2], Wbh[2], Wbl[2];                   // 32 VGPR
  XLOAD(X0h, X0l, 0);
  XLOAD(X1h, X1l, 1);
  XLOAD(X2h, X2l, 2);
  WLOAD(Wah, Wal, 0, 0);

  for (int g = 0; g < 27; g += 3) {        // its 0..26, branch-free bodies
    IT_BODY(X0h, X0l, g + 0, 1, 1);
    IT_BODY(X1h, X1l, g + 1, 1, 1);
    IT_BODY(X2h, X2l, g + 2, 1, 1);
  }
  IT_BODY(X0h, X0l, 27, 1, 1);             // loads X0 <- 30
  IT_BODY(X1h, X1l, 28, 1, 1);             // loads X1 <- 31
  IT_BODY(X2h, X2l, 29, 1, 0);
  IT_BODY(X0h, X0l, 30, 1, 0);
  IT_BODY(X1h, X1l, 31, 0, 0);

  // epilogue A: +b1, relu, split h -> LDS swizzled (C/D: col=lo, row=quad*4+i)
#pragma unroll
  for (int nt = 0; nt < 4; ++nt) {
    float b1v = b1[(size_t)k * NH + wv * 64 + nt * 16 + lo];
#pragma unroll
    for (int mt = 0; mt < 4; ++mt)
#pragma unroll
      for (int i = 0; i < 4; ++i) {
        float v = acc1[mt][nt][i] + b1v;
        v = v > 0.f ? v : 0.f;
        unsigned short vh, vl;
        split2(v, vh, vl);
        int row = mt * 16 + quad * 4 + i, col = wv * 64 + nt * 16 + lo;
        int sc = col ^ ((row & 7) << 3);
        s.hs.h[row][sc] = vh;
        s.hs.l[row][sc] = vl;
      }
  }
  __syncthreads();   // the ONE inter-phase barrier

  // ---------- phase B: recon = h@W2+b2. Wave wv owns d2-strip [wv*256, +256).
  // h A-frags dt-invariant: hold a 2-row-tile chunk in registers (128 VGPR)
  // and stream W2 frags (disjoint per wave, L2-resident).
  float eacc[4][4];
#pragma unroll
  for (int mt = 0; mt < 4; ++mt)
#pragma unroll
    for (int i = 0; i < 4; ++i) eacc[mt][i] = 0.f;

  const int w2base = ((k * 64 + wv * 16) * 8) * 512 + lane * 8;

  for (int mc = 0; mc < 2; ++mc) {
    s16x8 hh[2][8], hl[2][8];
#pragma unroll
    for (int m2 = 0; m2 < 2; ++m2) {
      int row = (mc * 2 + m2) * 16 + lo;
      int rbase = row * 256;
      int sw = (row & 7) << 3;
#pragma unroll
      for (int ks = 0; ks < 8; ++ks) {
        int off = rbase + ((ks * 32 + quad * 8) ^ sw);
        hh[m2][ks] = *(const s16x8*)(&s.hs.h[0][0] + off);
        hl[m2][ks] = *(const s16x8*)(&s.hs.l[0][0] + off);
      }
    }
    for (int dt = 0; dt < 16; ++dt) {
      f32x4 acc2[2];
      acc2[0] = (f32x4){0.f, 0.f, 0.f, 0.f};
      acc2[1] = (f32x4){0.f, 0.f, 0.f, 0.f};
#pragma unroll
      for (int ks = 0; ks < 8; ++ks) {
        int wo = w2base + dt * 4096 + ks * 512;
        s16x8 bh = *(const s16x8*)&w2ph[wo];
        s16x8 bl = *(const s16x8*)&w2pl[wo];
#pragma unroll
        for (int m2 = 0; m2 < 2; ++m2) {
          acc2[m2] = __builtin_amdgcn_mfma_f32_16x16x32_bf16(hh[m2][ks], bh, acc2[m2], 0, 0, 0);
          acc2[m2] = __builtin_amdgcn_mfma_f32_16x16x32_bf16(hh[m2][ks], bl, acc2[m2], 0, 0, 0);
          acc2[m2] = __builtin_amdgcn_mfma_f32_16x16x32_bf16(hl[m2][ks], bh, acc2[m2], 0, 0, 0);
        }
      }
      const int d2 = wv * 256 + dt * 16 + lo;
      float b2v = b2[(size_t)k * ND + d2];
#pragma unroll
      for (int m2 = 0; m2 < 2; ++m2)
#pragma unroll
        for (int i = 0; i < 4; ++i) {
          int row = (mc * 2 + m2) * 16 + quad * 4 + i;
          float rec = acc2[m2][i] + b2v;
          float xv = x[(size_t)(r0 + row) * ND + d2];
          float dd = rec - xv;
          eacc[mc * 2 + m2][i] += dd * dd;
        }
    }
  }

  __syncthreads();   // all hs reads done before errp aliases the union
#pragma unroll
  for (int mt = 0; mt < 4; ++mt)
#pragma unroll
    for (int i = 0; i < 4; ++i) {
      float v = eacc[mt][i];
      v += __shfl_xor(v, 1, 16);
      v += __shfl_xor(v, 2, 16);
      v += __shfl_xor(v, 4, 16);
      v += __shfl_xor(v, 8, 16);
      if (lo == 0) s.errp[wv][mt * 16 + quad * 4 + i] = v;
    }
  __syncthreads();
  if (tid < 64)
    err[(size_t)k * NB + r0 + tid] =
        (s.errp[0][tid] + s.errp[1][tid] + s.errp[2][tid] + s.errp[3][tid]) * (1.0f / (float)ND);
}

// ---- argmin + bucket rows per expert
__global__ __launch_bounds__(256) void ae_argmin(const float* __restrict__ err,
                                                 unsigned int* __restrict__ cnt,
                                                 int* __restrict__ bucket) {
  __shared__ unsigned int lc[KE];
  __shared__ unsigned int base[KE];
  int tid = threadIdx.x;
  if (tid < KE) lc[tid] = 0;
  __syncthreads();
  int b = blockIdx.x * 256 + tid;
  float best = err[b];
  int kmin = 0;
#pragma unroll
  for (int j = 1; j < KE; ++j) {
    float e = err[(size_t)j * NB + b];
    if (e < best) { best = e; kmin = j; }   // strict < == first-min (jnp.argmin)
  }
  unsigned int lpos = atomicAdd(&lc[kmin], 1u);
  __syncthreads();
  if (tid < KE) base[tid] = atomicAdd(&cnt[tid], lc[tid]);
  __syncthreads();
  bucket[(size_t)kmin * NB + (int)(base[kmin] + lpos)] = b;
}

// ---- pass 2: recompute winner rows (bf16-hi, packed W frags), write f32 out
__global__ __launch_bounds__(256) void ae_pass2(
    const float* __restrict__ x,
    const unsigned short* __restrict__ w1ph, const float* __restrict__ b1,
    const unsigned short* __restrict__ w2ph, const float* __restrict__ b2,
    const unsigned int* __restrict__ cnt, const int* __restrict__ bucket,
    float* __restrict__ out) {
  __shared__ unsigned short hs[64][NH + 8];   // 33792 B
  __shared__ unsigned short xs[64][40];       // 5120 B
  __shared__ int rid[64];

  const int k = blockIdx.x & 7;
  const int cv = (int)cnt[k];
  const int t0 = (blockIdx.x >> 3) * 64;
  if (t0 >= cv) return;                     // uniform exit before any barrier
  const int nrows = min(64, cv - t0);

  const int tid = threadIdx.x;
  const int wv = tid >> 6;
  const int lane = tid & 63;
  const int lo = lane & 15;
  const int quad = lane >> 4;
  const int srow = tid >> 2, scol = (tid & 3) * 8;

  if (tid < 64) {
    int idx = t0 + tid;
    rid[tid] = bucket[(size_t)k * NB + (idx < cv ? idx : t0)];
  }
  __syncthreads();
  const int grow = rid[srow];

  f32x4 acc1[4][4];
#pragma unroll
  for (int mt = 0; mt < 4; ++mt)
#pragma unroll
    for (int nt = 0; nt < 4; ++nt) acc1[mt][nt] = (f32x4){0.f, 0.f, 0.f, 0.f};

  for (int it = 0; it < 32; ++it) {
    float4 xa = *(const float4*)&x[(size_t)grow * ND + it * 32 + scol];
    float4 xb = *(const float4*)&x[(size_t)grow * ND + it * 32 + scol + 4];
    s16x8 bfr[4];
#pragma unroll
    for (int nt = 0; nt < 4; ++nt)
      bfr[nt] = *(const s16x8*)&w1ph[(((size_t)(k * 16 + wv * 4 + nt) * 32) + it) * 512 + lane * 8];
    __syncthreads();   // prev frag reads done
    unsigned short t[8];
    t[0] = f2bf(xa.x); t[1] = f2bf(xa.y); t[2] = f2bf(xa.z); t[3] = f2bf(xa.w);
    t[4] = f2bf(xb.x); t[5] = f2bf(xb.y); t[6] = f2bf(xb.z); t[7] = f2bf(xb.w);
    *(u16x8*)&xs[srow][scol] = *(u16x8*)t;
    __syncthreads();
    s16x8 af[4];
#pragma unroll
    for (int mt = 0; mt < 4; ++mt) af[mt] = *(const s16x8*)&xs[mt * 16 + lo][quad * 8];
#pragma unroll
    for (int mt = 0; mt < 4; ++mt)
#pragma unroll
      for (int nt = 0; nt < 4; ++nt)
        acc1[mt][nt] = __builtin_amdgcn_mfma_f32_16x16x32_bf16(af[mt], bfr[nt], acc1[mt][nt], 0, 0, 0);
  }
  __syncthreads();

#pragma unroll
  for (int nt = 0; nt < 4; ++nt) {
    float b1v = b1[(size_t)k * NH + wv * 64 + nt * 16 + lo];
#pragma unroll
    for (int mt = 0; mt < 4; ++mt)
#pragma unroll
      for (int i = 0; i < 4; ++i) {
        float v = acc1[mt][nt][i] + b1v;
        v = v > 0.f ? v : 0.f;
        hs[mt * 16 + quad * 4 + i][wv * 64 + nt * 16 + lo] = f2bf(v);
      }
  }
  __syncthreads();

  // phase B: wave wv owns rows [wv*16, +16); d2 chunks of 32; no barriers.
  for (int c = 0; c < 32; ++c) {
    f32x4 acc2[2];
    acc2[0] = (f32x4){0.f, 0.f, 0.f, 0.f};
    acc2[1] = (f32x4){0.f, 0.f, 0.f, 0.f};
#pragma unroll
    for (int ks = 0; ks < 8; ++ks) {
      s16x8 af = *(const s16x8*)&hs[wv * 16 + lo][ks * 32 + quad * 8];
#pragma unroll
      for (int nt = 0; nt < 2; ++nt) {
        s16x8 bfr = *(const s16x8*)&w2ph[(((size_t)(k * 64 + c * 2 + nt) * 8) + ks) * 512 + lane * 8];
        acc2[nt] = __builtin_amdgcn_mfma_f32_16x16x32_bf16(af, bfr, acc2[nt], 0, 0, 0);
      }
    }
#pragma unroll
    for (int nt = 0; nt < 2; ++nt) {
      float b2v = b2[(size_t)k * ND + c * 32 + nt * 16 + lo];
#pragma unroll
      for (int i = 0; i < 4; ++i) {
        int row = wv * 16 + quad * 4 + i;
        if (row < nrows)
          out[(size_t)rid[row] * ND + c * 32 + nt * 16 + lo] = acc2[nt][i] + b2v;
      }
    }
  }
}

extern "C" void kernel_launch(void* const* d_in, const int* in_sizes, int n_in,
                              void* d_out, int out_size, void* d_ws, size_t ws_size,
                              hipStream_t stream) {
  (void)in_sizes; (void)n_in; (void)out_size; (void)ws_size;
  const float* x  = (const float*)d_in[0];
  const float* W1 = (const float*)d_in[1];
  const float* b1 = (const float*)d_in[2];
  const float* W2 = (const float*)d_in[3];
  const float* b2 = (const float*)d_in[4];
  float* out = (float*)d_out;

  char* ws = (char*)d_ws;
  const size_t szW = (size_t)KE * ND * NH * sizeof(unsigned short);  // 4 MB
  const size_t szX = (size_t)NB * ND * sizeof(unsigned short);       // 16.78 MB
  unsigned short* w1ph = (unsigned short*)(ws);
  unsigned short* w1pl = (unsigned short*)(ws + szW);
  unsigned short* w2ph = (unsigned short*)(ws + 2 * szW);
  unsigned short* w2pl = (unsigned short*)(ws + 3 * szW);
  unsigned short* xph  = (unsigned short*)(ws + 4 * szW);
  unsigned short* xpl  = (unsigned short*)(ws + 4 * szW + szX);
  char* tail           = ws + 4 * szW + 2 * szX;
  float* err           = (float*)tail;
  int* bucket          = (int*)(tail + (size_t)KE * NB * sizeof(float));
  unsigned int* cnt    = (unsigned int*)(tail + (size_t)KE * NB * sizeof(float)
                                         + (size_t)KE * NB * sizeof(int));
  // ws use ~50 MB

  pack_all<<<6144, 256, 0, stream>>>(W1, w1ph, w1pl, W2, w2ph, w2pl, x, xph, xpl, cnt);
  ae_pass1<<<1024, 256, 0, stream>>>(xph, xpl, x, w1ph, w1pl, b1, w2ph, w2pl, b2, err);
  ae_argmin<<<NB / 256, 256, 0, stream>>>(err, cnt, bucket);
  ae_pass2<<<1024, 256, 0, stream>>>(x, w1ph, b1, w2ph, b2, cnt, bucket, out);
}

// Round 9
// 446.179 us; speedup vs baseline: 1.6225x; 1.0082x over previous
//
#include <hip/hip_runtime.h>

// f32 I/O. K=8 expert AEs, B=8192, D=1024, H=256.
//   h = relu(x @ W1[k] + b1[k]); recon = h @ W2[k] + b2[k]
//   err[k,b] = mean((recon-x)^2); out[b] = recon[argmin_k err, b]
// Precision (validated R2): pass1 err via split-bf16 hi/lo 3-product GEMMs;
// pass2 winner recon plain bf16-hi.
// CHAMPION = R10 (verified 422.4us, pass1 236us, MfmaUtil 39%): R6 dataflow
// (2-stage reg dbuf phase A; phase B h-in-regs per mc-pass, W2 streamed 2x)
// + [r_hi|k|r_lo] block decode. Structural escape attempts, all dead:
//   R8 reg-staged LDS ring -> spill; R9 per-ks LDS reads -> LDS-pipe bound;
//   R11 occupancy cap -> allocator spill @84 VGPR; R12 3-stage reg pipeline
//   -> compiler folds to 128 VGPR, -8%; R7/R13 global_load_lds -> container
//   crash (2x) -> ABANDONED. Diagnosis: with 64-AGPR acc live, arch VGPRs
//   pin at 128 -> 2 waves/SIMD is the operating point; ~40% MfmaUtil is this
//   structure's latency-exposure ceiling.
// R14 (this rev) = exact R10 champion + T5 s_setprio(1) around MFMA clusters
// (phase A stages + phase B ks-loops). Both phases are barrier-free ->
// waves drift into different roles (load-issuing vs MFMA) -> setprio has
// something to arbitrate (attn-like regime, m191 +4-7%; not GEMM-lockstep
// m190 null). Zero correctness risk; if flat, structure is at ceiling.

#define KE 8
#define NB 8192
#define ND 1024
#define NH 256

typedef float f32x4 __attribute__((ext_vector_type(4)));
typedef short s16x8 __attribute__((ext_vector_type(8)));
typedef unsigned short u16x8 __attribute__((ext_vector_type(8)));

__device__ __forceinline__ float bf2f(unsigned short h) {
  union { unsigned int u; float f; } v; v.u = ((unsigned int)h) << 16; return v.f;
}
__device__ __forceinline__ unsigned short f2bf(float f) {
  union { unsigned int u; float f; } v; v.f = f;
  unsigned int u = v.u;
  u += 0x7fffu + ((u >> 16) & 1u);   // RTNE
  return (unsigned short)(u >> 16);
}
__device__ __forceinline__ void split2(float x, unsigned short& hi, unsigned short& lo) {
  hi = f2bf(x);
  lo = f2bf(x - bf2f(hi));
}

// ---- fused pack: W1, W2, x -> frag-ordered hi/lo arrays; also zeroes cnt.
__global__ __launch_bounds__(256) void pack_all(
    const float* __restrict__ W1, unsigned short* __restrict__ w1oh, unsigned short* __restrict__ w1ol,
    const float* __restrict__ W2, unsigned short* __restrict__ w2oh, unsigned short* __restrict__ w2ol,
    const float* __restrict__ xin, unsigned short* __restrict__ xoh, unsigned short* __restrict__ xol,
    unsigned int* __restrict__ cnt) {
  const int bx = blockIdx.x;
  const int tid = threadIdx.x;
  if (bx == 0 && tid < KE) cnt[tid] = 0;

  if (bx < 1024) {                           // ---- pack W1
    int gid = bx * 256 + tid;
    int L = gid & 63;
    int g = gid >> 6;
    int ks = g & 31;
    int ct = (g >> 5) & 15;
    int k = g >> 9;
    int col = ct * 16 + (L & 15);
    int kd0 = ks * 32 + (L >> 4) * 8;
    unsigned short th[8], tl[8];
#pragma unroll
    for (int j = 0; j < 8; ++j) {
      float v = W1[((size_t)k * ND + kd0 + j) * NH + col];
      split2(v, th[j], tl[j]);
    }
    size_t o = ((size_t)g * 64 + L) * 8;
    *(u16x8*)&w1oh[o] = *(u16x8*)th;
    *(u16x8*)&w1ol[o] = *(u16x8*)tl;
  } else if (bx < 2048) {                    // ---- pack W2
    int gid = (bx - 1024) * 256 + tid;
    int L = gid & 63;
    int g = gid >> 6;
    int ks = g & 7;
    int dt = (g >> 3) & 63;
    int k = g >> 9;
    int d2 = dt * 16 + (L & 15);
    int h0 = ks * 32 + (L >> 4) * 8;
    unsigned short th[8], tl[8];
#pragma unroll
    for (int j = 0; j < 8; ++j) {
      float v = W2[((size_t)k * NH + h0 + j) * ND + d2];
      split2(v, th[j], tl[j]);
    }
    size_t o = ((size_t)g * 64 + L) * 8;
    *(u16x8*)&w2oh[o] = *(u16x8*)th;
    *(u16x8*)&w2ol[o] = *(u16x8*)tl;
  } else {                                   // ---- pack x
    int gid = (bx - 2048) * 256 + tid;
    int L = gid & 63;
    int g = gid >> 6;
    int ks = g & 31;
    int rt = g >> 5;
    int row = rt * 16 + (L & 15);
    int kd0 = ks * 32 + (L >> 4) * 8;
    float4 a = *(const float4*)&xin[(size_t)row * ND + kd0];
    float4 b = *(const float4*)&xin[(size_t)row * ND + kd0 + 4];
    unsigned short th[8], tl[8];
    split2(a.x, th[0], tl[0]); split2(a.y, th[1], tl[1]);
    split2(a.z, th[2], tl[2]); split2(a.w, th[3], tl[3]);
    split2(b.x, th[4], tl[4]); split2(b.y, th[5], tl[5]);
    split2(b.z, th[6], tl[6]); split2(b.w, th[7], tl[7]);
    size_t o = ((size_t)g * 64 + L) * 8;
    *(u16x8*)&xoh[o] = *(u16x8*)th;
    *(u16x8*)&xol[o] = *(u16x8*)tl;
  }
}

// load one phase-A stage (16 frags, 256B/lane) into named register buffers
#define LOAD_STAGE(ah, al, bh, bl, it)                  \
  do {                                                  \
    _Pragma("unroll")                                   \
    for (int q_ = 0; q_ < 4; ++q_) {                    \
      int o_ = xo[q_] + (it) * 512;                     \
      ah[q_] = *(const s16x8*)&xph[o_];                 \
      al[q_] = *(const s16x8*)&xpl[o_];                 \
    }                                                   \
    _Pragma("unroll")                                   \
    for (int q_ = 0; q_ < 4; ++q_) {                    \
      int o_ = wo1[q_] + (it) * 512;                    \
      bh[q_] = *(const s16x8*)&w1ph[o_];                \
      bl[q_] = *(const s16x8*)&w1pl[o_];                \
    }                                                   \
  } while (0)

// 48 MFMAs (3-product split) on one stage, wrapped in setprio(1) [T5]
#define MFMA_STAGE(ah, al, bh, bl)                                                                   \
  do {                                                                                               \
    __builtin_amdgcn_s_setprio(1);                                                                   \
    _Pragma("unroll")                                                                                \
    for (int nt_ = 0; nt_ < 4; ++nt_)                                                                \
      _Pragma("unroll")                                                                              \
      for (int mt_ = 0; mt_ < 4; ++mt_) {                                                            \
        acc1[mt_][nt_] = __builtin_amdgcn_mfma_f32_16x16x32_bf16(ah[mt_], bh[nt_], acc1[mt_][nt_], 0, 0, 0); \
        acc1[mt_][nt_] = __builtin_amdgcn_mfma_f32_16x16x32_bf16(ah[mt_], bl[nt_], acc1[mt_][nt_], 0, 0, 0); \
        acc1[mt_][nt_] = __builtin_amdgcn_mfma_f32_16x16x32_bf16(al[mt_], bh[nt_], acc1[mt_][nt_], 0, 0, 0); \
      }                                                                                              \
    __builtin_amdgcn_s_setprio(0);                                                                   \
  } while (0)

// ---- pass 1: split-precision err[K][B]. BM=64, grid 1024.
// Champion decode: bx bits [r_hi | k(3b) | r_lo(3b)] (R10, verified 422us).
__global__ __launch_bounds__(256, 2) void ae_pass1(
    const unsigned short* __restrict__ xph, const unsigned short* __restrict__ xpl,
    const float* __restrict__ x,
    const unsigned short* __restrict__ w1ph, const unsigned short* __restrict__ w1pl,
    const float* __restrict__ b1,
    const unsigned short* __restrict__ w2ph, const unsigned short* __restrict__ w2pl,
    const float* __restrict__ b2, float* __restrict__ err) {
  __shared__ union {
    struct { unsigned short h[64][256]; unsigned short l[64][256]; } hs;  // 65536 B
    float errp[4][64];
  } s;

  const int tid = threadIdx.x;
  const int wv = tid >> 6;
  const int lane = tid & 63;
  const int lo = lane & 15;
  const int quad = lane >> 4;
  const int k = (blockIdx.x >> 3) & 7;
  const int rtile = (int)(((blockIdx.x >> 6) << 3) | (blockIdx.x & 7));
  const int r0 = rtile * 64;

  // ---------- phase A: h = relu(x@W1+b1). Barrier-free, register-pipelined.
  int xo[4], wo1[4];
#pragma unroll
  for (int mt = 0; mt < 4; ++mt) xo[mt] = ((rtile * 4 + mt) * 32) * 512 + lane * 8;
#pragma unroll
  for (int nt = 0; nt < 4; ++nt) wo1[nt] = ((k * 16 + wv * 4 + nt) * 32) * 512 + lane * 8;

  f32x4 acc1[4][4];
#pragma unroll
  for (int mt = 0; mt < 4; ++mt)
#pragma unroll
    for (int nt = 0; nt < 4; ++nt) acc1[mt][nt] = (f32x4){0.f, 0.f, 0.f, 0.f};

  s16x8 Aah[4], Aal[4], Abh[4], Abl[4];
  s16x8 Bah[4], Bal[4], Bbh[4], Bbl[4];
  LOAD_STAGE(Aah, Aal, Abh, Abl, 0);
  LOAD_STAGE(Bah, Bal, Bbh, Bbl, 1);
  for (int it = 0; it < 32; it += 2) {
    MFMA_STAGE(Aah, Aal, Abh, Abl);
    if (it + 2 < 32) LOAD_STAGE(Aah, Aal, Abh, Abl, it + 2);
    MFMA_STAGE(Bah, Bal, Bbh, Bbl);
    if (it + 3 < 32) LOAD_STAGE(Bah, Bal, Bbh, Bbl, it + 3);
  }

  // epilogue A: +b1, relu, split h -> LDS swizzled (C/D: col=lo, row=quad*4+i)
#pragma unroll
  for (int nt = 0; nt < 4; ++nt) {
    float b1v = b1[(size_t)k * NH + wv * 64 + nt * 16 + lo];
#pragma unroll
    for (int mt = 0; mt < 4; ++mt)
#pragma unroll
      for (int i = 0; i < 4; ++i) {
        float v = acc1[mt][nt][i] + b1v;
        v = v > 0.f ? v : 0.f;
        unsigned short vh, vl;
        split2(v, vh, vl);
        int row = mt * 16 + quad * 4 + i, col = wv * 64 + nt * 16 + lo;
        int sc = col ^ ((row & 7) << 3);
        s.hs.h[row][sc] = vh;
        s.hs.l[row][sc] = vl;
      }
  }
  __syncthreads();   // the ONE inter-phase barrier

  // ---------- phase B: recon = h@W2+b2. Wave wv owns d2-strip [wv*256, +256).
  // h A-frags dt-invariant: hold a 2-row-tile chunk in registers (128 VGPR)
  // and stream W2 frags (disjoint per wave).
  float eacc[4][4];
#pragma unroll
  for (int mt = 0; mt < 4; ++mt)
#pragma unroll
    for (int i = 0; i < 4; ++i) eacc[mt][i] = 0.f;

  const int w2base = ((k * 64 + wv * 16) * 8) * 512 + lane * 8;

  for (int mc = 0; mc < 2; ++mc) {
    s16x8 hh[2][8], hl[2][8];
#pragma unroll
    for (int m2 = 0; m2 < 2; ++m2) {
      int row = (mc * 2 + m2) * 16 + lo;
      int rbase = row * 256;
      int sw = (row & 7) << 3;
#pragma unroll
      for (int ks = 0; ks < 8; ++ks) {
        int off = rbase + ((ks * 32 + quad * 8) ^ sw);
        hh[m2][ks] = *(const s16x8*)(&s.hs.h[0][0] + off);
        hl[m2][ks] = *(const s16x8*)(&s.hs.l[0][0] + off);
      }
    }
    for (int dt = 0; dt < 16; ++dt) {
      f32x4 acc2[2];
      acc2[0] = (f32x4){0.f, 0.f, 0.f, 0.f};
      acc2[1] = (f32x4){0.f, 0.f, 0.f, 0.f};
      __builtin_amdgcn_s_setprio(1);   // [T5] MFMA-dense region
#pragma unroll
      for (int ks = 0; ks < 8; ++ks) {
        int wo = w2base + dt * 4096 + ks * 512;
        s16x8 bh = *(const s16x8*)&w2ph[wo];
        s16x8 bl = *(const s16x8*)&w2pl[wo];
#pragma unroll
        for (int m2 = 0; m2 < 2; ++m2) {
          acc2[m2] = __builtin_amdgcn_mfma_f32_16x16x32_bf16(hh[m2][ks], bh, acc2[m2], 0, 0, 0);
          acc2[m2] = __builtin_amdgcn_mfma_f32_16x16x32_bf16(hh[m2][ks], bl, acc2[m2], 0, 0, 0);
          acc2[m2] = __builtin_amdgcn_mfma_f32_16x16x32_bf16(hl[m2][ks], bh, acc2[m2], 0, 0, 0);
        }
      }
      __builtin_amdgcn_s_setprio(0);
      const int d2 = wv * 256 + dt * 16 + lo;
      float b2v = b2[(size_t)k * ND + d2];
#pragma unroll
      for (int m2 = 0; m2 < 2; ++m2)
#pragma unroll
        for (int i = 0; i < 4; ++i) {
          int row = (mc * 2 + m2) * 16 + quad * 4 + i;
          float rec = acc2[m2][i] + b2v;
          float xv = x[(size_t)(r0 + row) * ND + d2];
          float dd = rec - xv;
          eacc[mc * 2 + m2][i] += dd * dd;
        }
    }
  }

  __syncthreads();   // all hs reads done before errp aliases the union
#pragma unroll
  for (int mt = 0; mt < 4; ++mt)
#pragma unroll
    for (int i = 0; i < 4; ++i) {
      float v = eacc[mt][i];
      v += __shfl_xor(v, 1, 16);
      v += __shfl_xor(v, 2, 16);
      v += __shfl_xor(v, 4, 16);
      v += __shfl_xor(v, 8, 16);
      if (lo == 0) s.errp[wv][mt * 16 + quad * 4 + i] = v;
    }
  __syncthreads();
  if (tid < 64)
    err[(size_t)k * NB + r0 + tid] =
        (s.errp[0][tid] + s.errp[1][tid] + s.errp[2][tid] + s.errp[3][tid]) * (1.0f / (float)ND);
}

// ---- argmin + bucket rows per expert
__global__ __launch_bounds__(256) void ae_argmin(const float* __restrict__ err,
                                                 unsigned int* __restrict__ cnt,
                                                 int* __restrict__ bucket) {
  __shared__ unsigned int lc[KE];
  __shared__ unsigned int base[KE];
  int tid = threadIdx.x;
  if (tid < KE) lc[tid] = 0;
  __syncthreads();
  int b = blockIdx.x * 256 + tid;
  float best = err[b];
  int kmin = 0;
#pragma unroll
  for (int j = 1; j < KE; ++j) {
    float e = err[(size_t)j * NB + b];
    if (e < best) { best = e; kmin = j; }   // strict < == first-min (jnp.argmin)
  }
  unsigned int lpos = atomicAdd(&lc[kmin], 1u);
  __syncthreads();
  if (tid < KE) base[tid] = atomicAdd(&cnt[tid], lc[tid]);
  __syncthreads();
  bucket[(size_t)kmin * NB + (int)(base[kmin] + lpos)] = b;
}

// ---- pass 2: recompute winner rows (bf16-hi, packed W frags), write f32 out
__global__ __launch_bounds__(256) void ae_pass2(
    const float* __restrict__ x,
    const unsigned short* __restrict__ w1ph, const float* __restrict__ b1,
    const unsigned short* __restrict__ w2ph, const float* __restrict__ b2,
    const unsigned int* __restrict__ cnt, const int* __restrict__ bucket,
    float* __restrict__ out) {
  __shared__ unsigned short hs[64][NH + 8];   // 33792 B
  __shared__ unsigned short xs[64][40];       // 5120 B
  __shared__ int rid[64];

  const int k = blockIdx.x & 7;
  const int cv = (int)cnt[k];
  const int t0 = (blockIdx.x >> 3) * 64;
  if (t0 >= cv) return;                     // uniform exit before any barrier
  const int nrows = min(64, cv - t0);

  const int tid = threadIdx.x;
  const int wv = tid >> 6;
  const int lane = tid & 63;
  const int lo = lane & 15;
  const int quad = lane >> 4;
  const int srow = tid >> 2, scol = (tid & 3) * 8;

  if (tid < 64) {
    int idx = t0 + tid;
    rid[tid] = bucket[(size_t)k * NB + (idx < cv ? idx : t0)];
  }
  __syncthreads();
  const int grow = rid[srow];

  f32x4 acc1[4][4];
#pragma unroll
  for (int mt = 0; mt < 4; ++mt)
#pragma unroll
    for (int nt = 0; nt < 4; ++nt) acc1[mt][nt] = (f32x4){0.f, 0.f, 0.f, 0.f};

  for (int it = 0; it < 32; ++it) {
    float4 xa = *(const float4*)&x[(size_t)grow * ND + it * 32 + scol];
    float4 xb = *(const float4*)&x[(size_t)grow * ND + it * 32 + scol + 4];
    s16x8 bfr[4];
#pragma unroll
    for (int nt = 0; nt < 4; ++nt)
      bfr[nt] = *(const s16x8*)&w1ph[(((size_t)(k * 16 + wv * 4 + nt) * 32) + it) * 512 + lane * 8];
    __syncthreads();   // prev frag reads done
    unsigned short t[8];
    t[0] = f2bf(xa.x); t[1] = f2bf(xa.y); t[2] = f2bf(xa.z); t[3] = f2bf(xa.w);
    t[4] = f2bf(xb.x); t[5] = f2bf(xb.y); t[6] = f2bf(xb.z); t[7] = f2bf(xb.w);
    *(u16x8*)&xs[srow][scol] = *(u16x8*)t;
    __syncthreads();
    s16x8 af[4];
#pragma unroll
    for (int mt = 0; mt < 4; ++mt) af[mt] = *(const s16x8*)&xs[mt * 16 + lo][quad * 8];
#pragma unroll
    for (int mt = 0; mt < 4; ++mt)
#pragma unroll
      for (int nt = 0; nt < 4; ++nt)
        acc1[mt][nt] = __builtin_amdgcn_mfma_f32_16x16x32_bf16(af[mt], bfr[nt], acc1[mt][nt], 0, 0, 0);
  }
  __syncthreads();

#pragma unroll
  for (int nt = 0; nt < 4; ++nt) {
    float b1v = b1[(size_t)k * NH + wv * 64 + nt * 16 + lo];
#pragma unroll
    for (int mt = 0; mt < 4; ++mt)
#pragma unroll
      for (int i = 0; i < 4; ++i) {
        float v = acc1[mt][nt][i] + b1v;
        v = v > 0.f ? v : 0.f;
        hs[mt * 16 + quad * 4 + i][wv * 64 + nt * 16 + lo] = f2bf(v);
      }
  }
  __syncthreads();

  // phase B: wave wv owns rows [wv*16, +16); d2 chunks of 32; no barriers.
  for (int c = 0; c < 32; ++c) {
    f32x4 acc2[2];
    acc2[0] = (f32x4){0.f, 0.f, 0.f, 0.f};
    acc2[1] = (f32x4){0.f, 0.f, 0.f, 0.f};
#pragma unroll
    for (int ks = 0; ks < 8; ++ks) {
      s16x8 af = *(const s16x8*)&hs[wv * 16 + lo][ks * 32 + quad * 8];
#pragma unroll
      for (int nt = 0; nt < 2; ++nt) {
        s16x8 bfr = *(const s16x8*)&w2ph[(((size_t)(k * 64 + c * 2 + nt) * 8) + ks) * 512 + lane * 8];
        acc2[nt] = __builtin_amdgcn_mfma_f32_16x16x32_bf16(af, bfr, acc2[nt], 0, 0, 0);
      }
    }
#pragma unroll
    for (int nt = 0; nt < 2; ++nt) {
      float b2v = b2[(size_t)k * ND + c * 32 + nt * 16 + lo];
#pragma unroll
      for (int i = 0; i < 4; ++i) {
        int row = wv * 16 + quad * 4 + i;
        if (row < nrows)
          out[(size_t)rid[row] * ND + c * 32 + nt * 16 + lo] = acc2[nt][i] + b2v;
      }
    }
  }
}

extern "C" void kernel_launch(void* const* d_in, const int* in_sizes, int n_in,
                              void* d_out, int out_size, void* d_ws, size_t ws_size,
                              hipStream_t stream) {
  (void)in_sizes; (void)n_in; (void)out_size; (void)ws_size;
  const float* x  = (const float*)d_in[0];
  const float* W1 = (const float*)d_in[1];
  const float* b1 = (const float*)d_in[2];
  const float* W2 = (const float*)d_in[3];
  const float* b2 = (const float*)d_in[4];
  float* out = (float*)d_out;

  char* ws = (char*)d_ws;
  const size_t szW = (size_t)KE * ND * NH * sizeof(unsigned short);  // 4 MB
  const size_t szX = (size_t)NB * ND * sizeof(unsigned short);       // 16.78 MB
  unsigned short* w1ph = (unsigned short*)(ws);
  unsigned short* w1pl = (unsigned short*)(ws + szW);
  unsigned short* w2ph = (unsigned short*)(ws + 2 * szW);
  unsigned short* w2pl = (unsigned short*)(ws + 3 * szW);
  unsigned short* xph  = (unsigned short*)(ws + 4 * szW);
  unsigned short* xpl  = (unsigned short*)(ws + 4 * szW + szX);
  char* tail           = ws + 4 * szW + 2 * szX;
  float* err           = (float*)tail;
  int* bucket          = (int*)(tail + (size_t)KE * NB * sizeof(float));
  unsigned int* cnt    = (unsigned int*)(tail + (size_t)KE * NB * sizeof(float)
                                         + (size_t)KE * NB * sizeof(int));
  // ws use ~50 MB

  pack_all<<<6144, 256, 0, stream>>>(W1, w1ph, w1pl, W2, w2ph, w2pl, x, xph, xpl, cnt);
  ae_pass1<<<1024, 256, 0, stream>>>(xph, xpl, x, w1ph, w1pl, b1, w2ph, w2pl, b2, err);
  ae_argmin<<<NB / 256, 256, 0, stream>>>(err, cnt, bucket);
  ae_pass2<<<1024, 256, 0, stream>>>(x, w1ph, b1, w2ph, b2, cnt, bucket, out);
}

// Round 10
// 407.420 us; speedup vs baseline: 1.7769x; 1.0951x over previous
//
#include <hip/hip_runtime.h>

// f32 I/O. K=8 expert AEs, B=8192, D=1024, H=256.
//   h = relu(x @ W1[k] + b1[k]); recon = h @ W2[k] + b2[k]
//   err[k,b] = mean((recon-x)^2); out[b] = recon[argmin_k err, b]
// Precision (validated R2): pass1 err via split-bf16 hi/lo 3-product GEMMs;
// pass2 winner recon plain bf16-hi (now: h from pass1's split computation).
// CHAMPION = R10 (verified 422.4us, pass1 236us, MfmaUtil 39%). Dead ends:
// R8 reg-staged ring (spill), R9 per-ks LDS reads (LDS-pipe), R11 wave-cap
// (allocator spill), R12 deeper reg pipeline (-8%), R7/R13 global_load_lds
// (container crash x2, abandoned), R14 setprio (-7%, lockstep co-blocks).
// pass1 is latency-pinned at 2 waves/SIMD (64-AGPR acc + 128 arch VGPR).
// NOTE: TCC FETCH_SIZE = L2 ingress (incl. L3 hits), ~7us of transfer ->
// traffic is not the cost; latency is. Remaining lever = the ~186us OUTSIDE
// pass1, dominated by pass2 which RECOMPUTES h for winner rows.
// R15 (this rev) = exact R10 + store-h fusion (ws_size-guarded):
//  - pass1 epilogue also stores vh -> h_glob[k][b][256] bf16 (32 MB, ~10us).
//  - ae_pass2_fast: no phase A. Lane's winner row fixed (grow=rid[wv*16+lo]);
//    preload its 8 h A-frags (128B) once; pure W2-stream phase B, 0 barriers
//    after rid, no LDS/x/W1. Old pass2 kept as fallback if ws too small.
// Tripwires: WRITE_SIZE ~33MB in pass1 is EXPECTED (h store, not spill).
// If total > 430 -> revert h path.

#define KE 8
#define NB 8192
#define ND 1024
#define NH 256

typedef float f32x4 __attribute__((ext_vector_type(4)));
typedef short s16x8 __attribute__((ext_vector_type(8)));
typedef unsigned short u16x8 __attribute__((ext_vector_type(8)));

__device__ __forceinline__ float bf2f(unsigned short h) {
  union { unsigned int u; float f; } v; v.u = ((unsigned int)h) << 16; return v.f;
}
__device__ __forceinline__ unsigned short f2bf(float f) {
  union { unsigned int u; float f; } v; v.f = f;
  unsigned int u = v.u;
  u += 0x7fffu + ((u >> 16) & 1u);   // RTNE
  return (unsigned short)(u >> 16);
}
__device__ __forceinline__ void split2(float x, unsigned short& hi, unsigned short& lo) {
  hi = f2bf(x);
  lo = f2bf(x - bf2f(hi));
}

// ---- fused pack: W1, W2, x -> frag-ordered hi/lo arrays; also zeroes cnt.
__global__ __launch_bounds__(256) void pack_all(
    const float* __restrict__ W1, unsigned short* __restrict__ w1oh, unsigned short* __restrict__ w1ol,
    const float* __restrict__ W2, unsigned short* __restrict__ w2oh, unsigned short* __restrict__ w2ol,
    const float* __restrict__ xin, unsigned short* __restrict__ xoh, unsigned short* __restrict__ xol,
    unsigned int* __restrict__ cnt) {
  const int bx = blockIdx.x;
  const int tid = threadIdx.x;
  if (bx == 0 && tid < KE) cnt[tid] = 0;

  if (bx < 1024) {                           // ---- pack W1
    int gid = bx * 256 + tid;
    int L = gid & 63;
    int g = gid >> 6;
    int ks = g & 31;
    int ct = (g >> 5) & 15;
    int k = g >> 9;
    int col = ct * 16 + (L & 15);
    int kd0 = ks * 32 + (L >> 4) * 8;
    unsigned short th[8], tl[8];
#pragma unroll
    for (int j = 0; j < 8; ++j) {
      float v = W1[((size_t)k * ND + kd0 + j) * NH + col];
      split2(v, th[j], tl[j]);
    }
    size_t o = ((size_t)g * 64 + L) * 8;
    *(u16x8*)&w1oh[o] = *(u16x8*)th;
    *(u16x8*)&w1ol[o] = *(u16x8*)tl;
  } else if (bx < 2048) {                    // ---- pack W2
    int gid = (bx - 1024) * 256 + tid;
    int L = gid & 63;
    int g = gid >> 6;
    int ks = g & 7;
    int dt = (g >> 3) & 63;
    int k = g >> 9;
    int d2 = dt * 16 + (L & 15);
    int h0 = ks * 32 + (L >> 4) * 8;
    unsigned short th[8], tl[8];
#pragma unroll
    for (int j = 0; j < 8; ++j) {
      float v = W2[((size_t)k * NH + h0 + j) * ND + d2];
      split2(v, th[j], tl[j]);
    }
    size_t o = ((size_t)g * 64 + L) * 8;
    *(u16x8*)&w2oh[o] = *(u16x8*)th;
    *(u16x8*)&w2ol[o] = *(u16x8*)tl;
  } else {                                   // ---- pack x
    int gid = (bx - 2048) * 256 + tid;
    int L = gid & 63;
    int g = gid >> 6;
    int ks = g & 31;
    int rt = g >> 5;
    int row = rt * 16 + (L & 15);
    int kd0 = ks * 32 + (L >> 4) * 8;
    float4 a = *(const float4*)&xin[(size_t)row * ND + kd0];
    float4 b = *(const float4*)&xin[(size_t)row * ND + kd0 + 4];
    unsigned short th[8], tl[8];
    split2(a.x, th[0], tl[0]); split2(a.y, th[1], tl[1]);
    split2(a.z, th[2], tl[2]); split2(a.w, th[3], tl[3]);
    split2(b.x, th[4], tl[4]); split2(b.y, th[5], tl[5]);
    split2(b.z, th[6], tl[6]); split2(b.w, th[7], tl[7]);
    size_t o = ((size_t)g * 64 + L) * 8;
    *(u16x8*)&xoh[o] = *(u16x8*)th;
    *(u16x8*)&xol[o] = *(u16x8*)tl;
  }
}

// load one phase-A stage (16 frags, 256B/lane) into named register buffers
#define LOAD_STAGE(ah, al, bh, bl, it)                  \
  do {                                                  \
    _Pragma("unroll")                                   \
    for (int q_ = 0; q_ < 4; ++q_) {                    \
      int o_ = xo[q_] + (it) * 512;                     \
      ah[q_] = *(const s16x8*)&xph[o_];                 \
      al[q_] = *(const s16x8*)&xpl[o_];                 \
    }                                                   \
    _Pragma("unroll")                                   \
    for (int q_ = 0; q_ < 4; ++q_) {                    \
      int o_ = wo1[q_] + (it) * 512;                    \
      bh[q_] = *(const s16x8*)&w1ph[o_];                \
      bl[q_] = *(const s16x8*)&w1pl[o_];                \
    }                                                   \
  } while (0)

// 48 MFMAs (3-product split) on one stage
#define MFMA_STAGE(ah, al, bh, bl)                                                                   \
  do {                                                                                               \
    _Pragma("unroll")                                                                                \
    for (int nt_ = 0; nt_ < 4; ++nt_)                                                                \
      _Pragma("unroll")                                                                              \
      for (int mt_ = 0; mt_ < 4; ++mt_) {                                                            \
        acc1[mt_][nt_] = __builtin_amdgcn_mfma_f32_16x16x32_bf16(ah[mt_], bh[nt_], acc1[mt_][nt_], 0, 0, 0); \
        acc1[mt_][nt_] = __builtin_amdgcn_mfma_f32_16x16x32_bf16(ah[mt_], bl[nt_], acc1[mt_][nt_], 0, 0, 0); \
        acc1[mt_][nt_] = __builtin_amdgcn_mfma_f32_16x16x32_bf16(al[mt_], bh[nt_], acc1[mt_][nt_], 0, 0, 0); \
      }                                                                                              \
  } while (0)

// ---- pass 1: split-precision err[K][B]. BM=64, grid 1024.
// Champion decode: bx bits [r_hi | k(3b) | r_lo(3b)] (R10, verified 422us).
__global__ __launch_bounds__(256, 2) void ae_pass1(
    const unsigned short* __restrict__ xph, const unsigned short* __restrict__ xpl,
    const float* __restrict__ x,
    const unsigned short* __restrict__ w1ph, const unsigned short* __restrict__ w1pl,
    const float* __restrict__ b1,
    const unsigned short* __restrict__ w2ph, const unsigned short* __restrict__ w2pl,
    const float* __restrict__ b2, float* __restrict__ err,
    unsigned short* __restrict__ hglob) {
  __shared__ union {
    struct { unsigned short h[64][256]; unsigned short l[64][256]; } hs;  // 65536 B
    float errp[4][64];
  } s;

  const int tid = threadIdx.x;
  const int wv = tid >> 6;
  const int lane = tid & 63;
  const int lo = lane & 15;
  const int quad = lane >> 4;
  const int k = (blockIdx.x >> 3) & 7;
  const int rtile = (int)(((blockIdx.x >> 6) << 3) | (blockIdx.x & 7));
  const int r0 = rtile * 64;

  // ---------- phase A: h = relu(x@W1+b1). Barrier-free, register-pipelined.
  int xo[4], wo1[4];
#pragma unroll
  for (int mt = 0; mt < 4; ++mt) xo[mt] = ((rtile * 4 + mt) * 32) * 512 + lane * 8;
#pragma unroll
  for (int nt = 0; nt < 4; ++nt) wo1[nt] = ((k * 16 + wv * 4 + nt) * 32) * 512 + lane * 8;

  f32x4 acc1[4][4];
#pragma unroll
  for (int mt = 0; mt < 4; ++mt)
#pragma unroll
    for (int nt = 0; nt < 4; ++nt) acc1[mt][nt] = (f32x4){0.f, 0.f, 0.f, 0.f};

  s16x8 Aah[4], Aal[4], Abh[4], Abl[4];
  s16x8 Bah[4], Bal[4], Bbh[4], Bbl[4];
  LOAD_STAGE(Aah, Aal, Abh, Abl, 0);
  LOAD_STAGE(Bah, Bal, Bbh, Bbl, 1);
  for (int it = 0; it < 32; it += 2) {
    MFMA_STAGE(Aah, Aal, Abh, Abl);
    if (it + 2 < 32) LOAD_STAGE(Aah, Aal, Abh, Abl, it + 2);
    MFMA_STAGE(Bah, Bal, Bbh, Bbl);
    if (it + 3 < 32) LOAD_STAGE(Bah, Bal, Bbh, Bbl, it + 3);
  }

  // epilogue A: +b1, relu, split h -> LDS swizzled; also store vh to h_glob
  // (winner-row reuse by ae_pass2_fast; uniform-branch disabled if null).
  const bool wh = (hglob != nullptr);
#pragma unroll
  for (int nt = 0; nt < 4; ++nt) {
    float b1v = b1[(size_t)k * NH + wv * 64 + nt * 16 + lo];
#pragma unroll
    for (int mt = 0; mt < 4; ++mt)
#pragma unroll
      for (int i = 0; i < 4; ++i) {
        float v = acc1[mt][nt][i] + b1v;
        v = v > 0.f ? v : 0.f;
        unsigned short vh, vl;
        split2(v, vh, vl);
        int row = mt * 16 + quad * 4 + i, col = wv * 64 + nt * 16 + lo;
        int sc = col ^ ((row & 7) << 3);
        s.hs.h[row][sc] = vh;
        s.hs.l[row][sc] = vl;
        if (wh) hglob[((size_t)k * NB + r0 + row) * NH + col] = vh;
      }
  }
  __syncthreads();   // the ONE inter-phase barrier

  // ---------- phase B: recon = h@W2+b2. Wave wv owns d2-strip [wv*256, +256).
  // h A-frags dt-invariant: hold a 2-row-tile chunk in registers (128 VGPR)
  // and stream W2 frags (disjoint per wave).
  float eacc[4][4];
#pragma unroll
  for (int mt = 0; mt < 4; ++mt)
#pragma unroll
    for (int i = 0; i < 4; ++i) eacc[mt][i] = 0.f;

  const int w2base = ((k * 64 + wv * 16) * 8) * 512 + lane * 8;

  for (int mc = 0; mc < 2; ++mc) {
    s16x8 hh[2][8], hl[2][8];
#pragma unroll
    for (int m2 = 0; m2 < 2; ++m2) {
      int row = (mc * 2 + m2) * 16 + lo;
      int rbase = row * 256;
      int sw = (row & 7) << 3;
#pragma unroll
      for (int ks = 0; ks < 8; ++ks) {
        int off = rbase + ((ks * 32 + quad * 8) ^ sw);
        hh[m2][ks] = *(const s16x8*)(&s.hs.h[0][0] + off);
        hl[m2][ks] = *(const s16x8*)(&s.hs.l[0][0] + off);
      }
    }
    for (int dt = 0; dt < 16; ++dt) {
      f32x4 acc2[2];
      acc2[0] = (f32x4){0.f, 0.f, 0.f, 0.f};
      acc2[1] = (f32x4){0.f, 0.f, 0.f, 0.f};
#pragma unroll
      for (int ks = 0; ks < 8; ++ks) {
        int wo = w2base + dt * 4096 + ks * 512;
        s16x8 bh = *(const s16x8*)&w2ph[wo];
        s16x8 bl = *(const s16x8*)&w2pl[wo];
#pragma unroll
        for (int m2 = 0; m2 < 2; ++m2) {
          acc2[m2] = __builtin_amdgcn_mfma_f32_16x16x32_bf16(hh[m2][ks], bh, acc2[m2], 0, 0, 0);
          acc2[m2] = __builtin_amdgcn_mfma_f32_16x16x32_bf16(hh[m2][ks], bl, acc2[m2], 0, 0, 0);
          acc2[m2] = __builtin_amdgcn_mfma_f32_16x16x32_bf16(hl[m2][ks], bh, acc2[m2], 0, 0, 0);
        }
      }
      const int d2 = wv * 256 + dt * 16 + lo;
      float b2v = b2[(size_t)k * ND + d2];
#pragma unroll
      for (int m2 = 0; m2 < 2; ++m2)
#pragma unroll
        for (int i = 0; i < 4; ++i) {
          int row = (mc * 2 + m2) * 16 + quad * 4 + i;
          float rec = acc2[m2][i] + b2v;
          float xv = x[(size_t)(r0 + row) * ND + d2];
          float dd = rec - xv;
          eacc[mc * 2 + m2][i] += dd * dd;
        }
    }
  }

  __syncthreads();   // all hs reads done before errp aliases the union
#pragma unroll
  for (int mt = 0; mt < 4; ++mt)
#pragma unroll
    for (int i = 0; i < 4; ++i) {
      float v = eacc[mt][i];
      v += __shfl_xor(v, 1, 16);
      v += __shfl_xor(v, 2, 16);
      v += __shfl_xor(v, 4, 16);
      v += __shfl_xor(v, 8, 16);
      if (lo == 0) s.errp[wv][mt * 16 + quad * 4 + i] = v;
    }
  __syncthreads();
  if (tid < 64)
    err[(size_t)k * NB + r0 + tid] =
        (s.errp[0][tid] + s.errp[1][tid] + s.errp[2][tid] + s.errp[3][tid]) * (1.0f / (float)ND);
}

// ---- argmin + bucket rows per expert
__global__ __launch_bounds__(256) void ae_argmin(const float* __restrict__ err,
                                                 unsigned int* __restrict__ cnt,
                                                 int* __restrict__ bucket) {
  __shared__ unsigned int lc[KE];
  __shared__ unsigned int base[KE];
  int tid = threadIdx.x;
  if (tid < KE) lc[tid] = 0;
  __syncthreads();
  int b = blockIdx.x * 256 + tid;
  float best = err[b];
  int kmin = 0;
#pragma unroll
  for (int j = 1; j < KE; ++j) {
    float e = err[(size_t)j * NB + b];
    if (e < best) { best = e; kmin = j; }   // strict < == first-min (jnp.argmin)
  }
  unsigned int lpos = atomicAdd(&lc[kmin], 1u);
  __syncthreads();
  if (tid < KE) base[tid] = atomicAdd(&cnt[tid], lc[tid]);
  __syncthreads();
  bucket[(size_t)kmin * NB + (int)(base[kmin] + lpos)] = b;
}

// ---- pass 2 FAST: h precomputed by pass1 -> phase B only, no LDS exchange.
// Lane serves winner row grow=rid[wv*16+lo] for the whole kernel; its 8 h
// A-frags (128B) preloaded once; then pure W2-stream + MFMA, no barriers.
__global__ __launch_bounds__(256) void ae_pass2_fast(
    const unsigned short* __restrict__ hglob,
    const unsigned short* __restrict__ w2ph, const float* __restrict__ b2,
    const unsigned int* __restrict__ cnt, const int* __restrict__ bucket,
    float* __restrict__ out) {
  __shared__ int rid[64];

  const int k = blockIdx.x & 7;
  const int cv = (int)cnt[k];
  const int t0 = (blockIdx.x >> 3) * 64;
  if (t0 >= cv) return;                     // uniform exit before any barrier
  const int nrows = min(64, cv - t0);

  const int tid = threadIdx.x;
  const int wv = tid >> 6;
  const int lane = tid & 63;
  const int lo = lane & 15;
  const int quad = lane >> 4;

  if (tid < 64) {
    int idx = t0 + tid;
    rid[tid] = bucket[(size_t)k * NB + (idx < cv ? idx : t0)];
  }
  __syncthreads();

  const int grow = rid[wv * 16 + lo];       // this lane's winner row
  s16x8 af[8];                              // its 8 A-frag slices (32 VGPR)
  const size_t hbase = ((size_t)k * NB + grow) * NH + quad * 8;
#pragma unroll
  for (int ks = 0; ks < 8; ++ks)
    af[ks] = *(const s16x8*)&hglob[hbase + ks * 32];

  for (int c = 0; c < 32; ++c) {
    f32x4 acc2[2];
    acc2[0] = (f32x4){0.f, 0.f, 0.f, 0.f};
    acc2[1] = (f32x4){0.f, 0.f, 0.f, 0.f};
#pragma unroll
    for (int ks = 0; ks < 8; ++ks) {
#pragma unroll
      for (int nt = 0; nt < 2; ++nt) {
        s16x8 bfr = *(const s16x8*)&w2ph[(((size_t)(k * 64 + c * 2 + nt) * 8) + ks) * 512 + lane * 8];
        acc2[nt] = __builtin_amdgcn_mfma_f32_16x16x32_bf16(af[ks], bfr, acc2[nt], 0, 0, 0);
      }
    }
#pragma unroll
    for (int nt = 0; nt < 2; ++nt) {
      float b2v = b2[(size_t)k * ND + c * 32 + nt * 16 + lo];
#pragma unroll
      for (int i = 0; i < 4; ++i) {
        int row = wv * 16 + quad * 4 + i;
        if (row < nrows)
          out[(size_t)rid[row] * ND + c * 32 + nt * 16 + lo] = acc2[nt][i] + b2v;
      }
    }
  }
}

// ---- pass 2 (fallback, ws too small): recompute winner rows from x
__global__ __launch_bounds__(256) void ae_pass2(
    const float* __restrict__ x,
    const unsigned short* __restrict__ w1ph, const float* __restrict__ b1,
    const unsigned short* __restrict__ w2ph, const float* __restrict__ b2,
    const unsigned int* __restrict__ cnt, const int* __restrict__ bucket,
    float* __restrict__ out) {
  __shared__ unsigned short hs[64][NH + 8];   // 33792 B
  __shared__ unsigned short xs[64][40];       // 5120 B
  __shared__ int rid[64];

  const int k = blockIdx.x & 7;
  const int cv = (int)cnt[k];
  const int t0 = (blockIdx.x >> 3) * 64;
  if (t0 >= cv) return;                     // uniform exit before any barrier
  const int nrows = min(64, cv - t0);

  const int tid = threadIdx.x;
  const int wv = tid >> 6;
  const int lane = tid & 63;
  const int lo = lane & 15;
  const int quad = lane >> 4;
  const int srow = tid >> 2, scol = (tid & 3) * 8;

  if (tid < 64) {
    int idx = t0 + tid;
    rid[tid] = bucket[(size_t)k * NB + (idx < cv ? idx : t0)];
  }
  __syncthreads();
  const int grow = rid[srow];

  f32x4 acc1[4][4];
#pragma unroll
  for (int mt = 0; mt < 4; ++mt)
#pragma unroll
    for (int nt = 0; nt < 4; ++nt) acc1[mt][nt] = (f32x4){0.f, 0.f, 0.f, 0.f};

  for (int it = 0; it < 32; ++it) {
    float4 xa = *(const float4*)&x[(size_t)grow * ND + it * 32 + scol];
    float4 xb = *(const float4*)&x[(size_t)grow * ND + it * 32 + scol + 4];
    s16x8 bfr[4];
#pragma unroll
    for (int nt = 0; nt < 4; ++nt)
      bfr[nt] = *(const s16x8*)&w1ph[(((size_t)(k * 16 + wv * 4 + nt) * 32) + it) * 512 + lane * 8];
    __syncthreads();   // prev frag reads done
    unsigned short t[8];
    t[0] = f2bf(xa.x); t[1] = f2bf(xa.y); t[2] = f2bf(xa.z); t[3] = f2bf(xa.w);
    t[4] = f2bf(xb.x); t[5] = f2bf(xb.y); t[6] = f2bf(xb.z); t[7] = f2bf(xb.w);
    *(u16x8*)&xs[srow][scol] = *(u16x8*)t;
    __syncthreads();
    s16x8 af[4];
#pragma unroll
    for (int mt = 0; mt < 4; ++mt) af[mt] = *(const s16x8*)&xs[mt * 16 + lo][quad * 8];
#pragma unroll
    for (int mt = 0; mt < 4; ++mt)
#pragma unroll
      for (int nt = 0; nt < 4; ++nt)
        acc1[mt][nt] = __builtin_amdgcn_mfma_f32_16x16x32_bf16(af[mt], bfr[nt], acc1[mt][nt], 0, 0, 0);
  }
  __syncthreads();

#pragma unroll
  for (int nt = 0; nt < 4; ++nt) {
    float b1v = b1[(size_t)k * NH + wv * 64 + nt * 16 + lo];
#pragma unroll
    for (int mt = 0; mt < 4; ++mt)
#pragma unroll
      for (int i = 0; i < 4; ++i) {
        float v = acc1[mt][nt][i] + b1v;
        v = v > 0.f ? v : 0.f;
        hs[mt * 16 + quad * 4 + i][wv * 64 + nt * 16 + lo] = f2bf(v);
      }
  }
  __syncthreads();

  // phase B: wave wv owns rows [wv*16, +16); d2 chunks of 32; no barriers.
  for (int c = 0; c < 32; ++c) {
    f32x4 acc2[2];
    acc2[0] = (f32x4){0.f, 0.f, 0.f, 0.f};
    acc2[1] = (f32x4){0.f, 0.f, 0.f, 0.f};
#pragma unroll
    for (int ks = 0; ks < 8; ++ks) {
      s16x8 af = *(const s16x8*)&hs[wv * 16 + lo][ks * 32 + quad * 8];
#pragma unroll
      for (int nt = 0; nt < 2; ++nt) {
        s16x8 bfr = *(const s16x8*)&w2ph[(((size_t)(k * 64 + c * 2 + nt) * 8) + ks) * 512 + lane * 8];
        acc2[nt] = __builtin_amdgcn_mfma_f32_16x16x32_bf16(af, bfr, acc2[nt], 0, 0, 0);
      }
    }
#pragma unroll
    for (int nt = 0; nt < 2; ++nt) {
      float b2v = b2[(size_t)k * ND + c * 32 + nt * 16 + lo];
#pragma unroll
      for (int i = 0; i < 4; ++i) {
        int row = wv * 16 + quad * 4 + i;
        if (row < nrows)
          out[(size_t)rid[row] * ND + c * 32 + nt * 16 + lo] = acc2[nt][i] + b2v;
      }
    }
  }
}

extern "C" void kernel_launch(void* const* d_in, const int* in_sizes, int n_in,
                              void* d_out, int out_size, void* d_ws, size_t ws_size,
                              hipStream_t stream) {
  (void)in_sizes; (void)n_in; (void)out_size;
  const float* x  = (const float*)d_in[0];
  const float* W1 = (const float*)d_in[1];
  const float* b1 = (const float*)d_in[2];
  const float* W2 = (const float*)d_in[3];
  const float* b2 = (const float*)d_in[4];
  float* out = (float*)d_out;

  char* ws = (char*)d_ws;
  const size_t szW = (size_t)KE * ND * NH * sizeof(unsigned short);  // 4 MB
  const size_t szX = (size_t)NB * ND * sizeof(unsigned short);       // 16.78 MB
  unsigned short* w1ph = (unsigned short*)(ws);
  unsigned short* w1pl = (unsigned short*)(ws + szW);
  unsigned short* w2ph = (unsigned short*)(ws + 2 * szW);
  unsigned short* w2pl = (unsigned short*)(ws + 3 * szW);
  unsigned short* xph  = (unsigned short*)(ws + 4 * szW);
  unsigned short* xpl  = (unsigned short*)(ws + 4 * szW + szX);
  char* tail           = ws + 4 * szW + 2 * szX;
  float* err           = (float*)tail;
  int* bucket          = (int*)(tail + (size_t)KE * NB * sizeof(float));
  unsigned int* cnt    = (unsigned int*)(tail + (size_t)KE * NB * sizeof(float)
                                         + (size_t)KE * NB * sizeof(int));
  // base use ~50.3 MB; optional h_glob appended (+32 MB, guarded by ws_size)
  size_t base = 4 * szW + 2 * szX + (size_t)KE * NB * (sizeof(float) + sizeof(int)) + 4096;
  size_t hbytes = (size_t)KE * NB * NH * sizeof(unsigned short);     // 32 MB
  unsigned short* hglob = (ws_size >= base + hbytes)
                              ? (unsigned short*)(ws + base) : nullptr;

  pack_all<<<6144, 256, 0, stream>>>(W1, w1ph, w1pl, W2, w2ph, w2pl, x, xph, xpl, cnt);
  ae_pass1<<<1024, 256, 0, stream>>>(xph, xpl, x, w1ph, w1pl, b1, w2ph, w2pl, b2, err, hglob);
  ae_argmin<<<NB / 256, 256, 0, stream>>>(err, cnt, bucket);
  if (hglob)
    ae_pass2_fast<<<1024, 256, 0, stream>>>(hglob, w2ph, b2, cnt, bucket, out);
  else
    ae_pass2<<<1024, 256, 0, stream>>>(x, w1ph, b1, w2ph, b2, cnt, bucket, out);
}